// Round 7
// baseline (7699.818 us; speedup 1.0000x reference)
//
#include <hip/hip_runtime.h>
#include <hip/hip_fp16.h>

#define NB 128
#define TT 256
#define MM 256
#define PP 256
#define QSCALE 2.8853900817779268f   // 2*log2(e)

typedef unsigned int uint;
typedef _Float16 hf2 __attribute__((ext_vector_type(2)));

__device__ __forceinline__ float dot2f(uint a, uint b, float c){
#if defined(__AMDGCN__) && __has_builtin(__builtin_amdgcn_fdot2)
    return __builtin_amdgcn_fdot2(__builtin_bit_cast(hf2, a), __builtin_bit_cast(hf2, b), c, false);
#else
    float2 fa = __half22float2(__builtin_bit_cast(__half2, a));
    float2 fb = __half22float2(__builtin_bit_cast(__half2, b));
    return fmaf(fa.x, fb.x, fmaf(fa.y, fb.y, c));
#endif
}

__device__ __forceinline__ float frcp(float x){ return __builtin_amdgcn_rcpf(x); }
#if defined(__AMDGCN__) && __has_builtin(__builtin_amdgcn_exp2f)
__device__ __forceinline__ float fexp2(float x){ return __builtin_amdgcn_exp2f(x); }
#else
__device__ __forceinline__ float fexp2(float x){ return exp2f(x); }
#endif
__device__ __forceinline__ float fsig(float x){ return frcp(1.f + __expf(-x)); }
__device__ __forceinline__ float ftanh(float x){ return fmaf(-2.f, frcp(1.f + __expf(2.f*x)), 1.f); }

__device__ __forceinline__ float wsum(float v){
    #pragma unroll
    for(int o=32;o;o>>=1) v += __shfl_xor(v,o);
    return v;
}

// 2 tanh-terms: acc += dot2(Wv2, 1/(Ep2*Eq2+1)) with f32 accumulate
__device__ __forceinline__ float term2(uint ep, uint eq, uint wv, float acc){
    hf2 d = __builtin_bit_cast(hf2, ep) * __builtin_bit_cast(hf2, eq)
          + hf2{(_Float16)1.f, (_Float16)1.f};
    const __half2 r = h2rcp(__builtin_bit_cast(__half2, d));
    return dot2f(__builtin_bit_cast(uint, r), wv, acc);
}

// preE[row, m] = exp2(QSCALE*(enc[row]@W1[:,m] + b1[m])) -> fp16  (Ep)
__global__ __launch_bounds__(256) void prep_pre(
    const float* __restrict__ enc, const float* __restrict__ W1,
    const float* __restrict__ b1, __half* __restrict__ preE)
{
    const int row0 = blockIdx.x * 32;
    const int col  = threadIdx.x;
    float acc[32];
    const float bias = b1[col];
    #pragma unroll
    for (int r=0;r<32;++r) acc[r]=bias;
    for (int k=0;k<256;k+=4){
        const float w0 = W1[(size_t)(k+0)*256+col];
        const float w1 = W1[(size_t)(k+1)*256+col];
        const float w2 = W1[(size_t)(k+2)*256+col];
        const float w3 = W1[(size_t)(k+3)*256+col];
        #pragma unroll
        for (int r=0;r<32;++r){
            const float4 e = *(const float4*)(enc + (size_t)(row0+r)*256 + k);
            acc[r] = fmaf(e.x,w0, fmaf(e.y,w1, fmaf(e.z,w2, fmaf(e.w,w3, acc[r]))));
        }
    }
    #pragma unroll
    for (int r=0;r<32;++r) preE[(size_t)(row0+r)*256+col] = __float2half(fexp2(acc[r]*QSCALE));
}

// Wr (256,1024) f32 -> Wr4[k4][j2] uint4: 4 k x 2 cols per 16B
__global__ __launch_bounds__(256) void pack_wr4(const float* __restrict__ Wr, uint4* __restrict__ Wp){
    const int idx = blockIdx.x*256 + threadIdx.x;   // 32768
    const int k4 = idx >> 9, j2 = idx & 511;
    const int k = 4*k4, j = 2*j2;
    const __half2 x = __floats2half2_rn(Wr[(size_t)(k+0)*1024+j],   Wr[(size_t)(k+1)*1024+j]);
    const __half2 y = __floats2half2_rn(Wr[(size_t)(k+2)*1024+j],   Wr[(size_t)(k+3)*1024+j]);
    const __half2 z = __floats2half2_rn(Wr[(size_t)(k+0)*1024+j+1], Wr[(size_t)(k+1)*1024+j+1]);
    const __half2 w = __floats2half2_rn(Wr[(size_t)(k+2)*1024+j+1], Wr[(size_t)(k+3)*1024+j+1]);
    Wp[idx] = make_uint4(__builtin_bit_cast(uint,x), __builtin_bit_cast(uint,y),
                         __builtin_bit_cast(uint,z), __builtin_bit_cast(uint,w));
}
// W2 (512,256) f32 * QSCALE -> Wp[k2*256 + m]
__global__ __launch_bounds__(256) void pack_w2(const float* __restrict__ W2, __half2* __restrict__ Wp){
    const int idx = blockIdx.x*256 + threadIdx.x;   // 65536
    const int k2 = idx >> 8, m = idx & 255;
    Wp[idx] = __floats2half2_rn(W2[(size_t)(2*k2)*256 + m]*QSCALE, W2[(size_t)(2*k2+1)*256 + m]*QSCALE);
}
// edot[row] = enc[row,:] . Wd[1:257]
__global__ __launch_bounds__(256) void prep_edot(
    const float* __restrict__ enc, const float* __restrict__ Wd, float* __restrict__ edot)
{
    const int row  = blockIdx.x*4 + (threadIdx.x>>6);
    const int lane = threadIdx.x & 63;
    const float4 e = *(const float4*)(enc + (size_t)row*256 + lane*4);
    float s = e.x*Wd[1+lane*4] + e.y*Wd[2+lane*4] + e.z*Wd[3+lane*4] + e.w*Wd[4+lane*4];
    s = wsum(s);
    if (lane==0) edot[row] = s;
}

// One block per batch element; 1024 threads; 4 barriers/step.
// Waves 8-15: Wr producer with 8-deep uint4 register preload across barriers.
// Score phase uses precomputed Ep=exp2(qp') and per-step Eq=exp2(q'); softmax
// max-subtraction dropped (scores bounded); e + partial sums folded into R4.
__global__ __launch_bounds__(1024, 4) void decoder_kernel(
    const float* __restrict__ data, const float* __restrict__ enc,
    const float* __restrict__ h0, const float* __restrict__ c0,
    const float* __restrict__ Wd, const float* __restrict__ bd,
    const float* __restrict__ Wk, const float* __restrict__ bl,
    const float* __restrict__ b2, const float* __restrict__ Wv,
    const float* __restrict__ bv,
    const uint4* __restrict__ Wr4,    // [64 k4][512 j2]
    const uint4* __restrict__ W2_p,   // [256 k2][64 uint4]
    const __half* __restrict__ preE,  // [B*T][256] Ep fp16
    const float* __restrict__ edot,   // [B*T]
    float* __restrict__ out)
{
    __shared__ __half s_pre[TT*MM];      // 131072 B (Ep, swizzled)
    __shared__ float s_red[2048];        // 8192 B
    __shared__ float s_z[1024];          // 4096 B
    __shared__ alignas(16) __half s_hh[PP];
    __shared__ alignas(16) __half s_ch[PP];
    __shared__ float s_h[PP], s_c[PP], s_score[TT];
    __shared__ float s_r2[32];
    __shared__ __half s_Wk[1024];
    __shared__ float s_bl[1024], s_b2[MM];
    __shared__ alignas(16) uint s_eqh[128];   // Eq fp16 pairs (per step)
    __shared__ alignas(16) uint s_wvh[128];   // Wv fp16 pairs
    __shared__ float s_edot[TT], s_data[TT];
    __shared__ float s_sc2[4];

    const int tid  = threadIdx.x;
    const int lane = tid & 63;
    const int wid  = tid >> 6;
    const int b    = blockIdx.x;

    s_Wk[tid] = __float2half(Wk[tid]);
    s_bl[tid] = bl[tid];
    if (tid < MM){
        s_b2[tid] = b2[tid]*QSCALE;
        const float h0v = h0[(size_t)b*PP+tid];
        const float c0v = c0[(size_t)b*PP+tid];
        s_h[tid]  = h0v;  s_hh[tid] = __float2half(h0v);
        s_c[tid]  = c0v;  s_ch[tid] = __float2half(c0v);
        s_edot[tid] = edot[(size_t)b*TT + tid];
    }
    if (tid < TT-1) s_data[tid] = data[(size_t)b*(TT-1)+tid];
    if (tid < 16) s_r2[tid] = (tid==0) ? 1.f : 0.f;   // den=1, num=0 for t=0
    if (tid < 128){
        const float2 w2 = *(const float2*)(Wv + 2*tid);
        s_wvh[tid] = __builtin_bit_cast(uint, __floats2half2_rn(w2.x, w2.y));
    }
    if (tid == 0){ s_sc2[0] = bd[0]; s_sc2[2] = Wd[0]; }
    if (tid < 64){
        const float4 w4 = *(const float4*)(Wv + 4*tid);
        float s = (w4.x+w4.y)+(w4.z+w4.w);
        s = wsum(s);
        if (tid==0) s_sc2[3] = (bv[0] + s) * (0.5f*QSCALE);   // C' = (bv+SumWv)*log2e
    }
    __syncthreads();

    const int p = tid - 512;             // producer thread id 0..511
    uint4 pb[8];                         // producer preload regs (static-indexed)
    const uint4* wc = Wr4 + ((tid >= 512) ? p : 0);
    const uint2* hu2 = (const uint2*)s_hh;

    // ---- prologue ----
    if (tid < 512){
        // stage Ep into LDS (swizzled): row t0 = tid>>1, 16 x 16B chunks
        const uint4* g = (const uint4*)(preE + (size_t)b*TT*MM);
        const int t0 = tid >> 1, cg = (tid & 1) * 16;
        const int rsw = (t0 & 15) << 4;
        #pragma unroll
        for (int i=0;i<16;++i){
            const int c = cg + i;
            *(uint4*)((char*)s_pre + t0*512 + ((c*16) ^ rsw)) = g[t0*32 + c];
        }
    } else {
        // z0 = h0 @ Wr (all 64 k4), then preload k4 0..7 for step-0 R2
        float a0=0.f,a1=0.f,a2=0.f,a3=0.f;
        #pragma unroll 8
        for (int k=0;k<64;++k){
            const uint4 w = wc[(size_t)k*512];
            const uint2 hp = hu2[k];
            a0=dot2f(w.x,hp.x,a0); a1=dot2f(w.y,hp.y,a1);
            a2=dot2f(w.z,hp.x,a2); a3=dot2f(w.w,hp.y,a3);
        }
        *(float2*)&s_z[2*p] = make_float2(a0+a1, a2+a3);
        #pragma unroll
        for (int i=0;i<8;++i) pb[i] = wc[(size_t)i*512];
    }
    __syncthreads();

    const float* erow_b = enc + (size_t)b*TT*MM;
    const int mq  = tid & 63;    // R2/epilogue: m-quad
    const int kc2 = tid >> 6;    // R2: k2-chunk 0..7; epilogue: t-chunk
    const int ttx = tid >> 1;    // R4: t row
    const int sub = tid & 1;     // R4: m half

    for (int t=0; t<TT-1; ++t){
        float a0=0.f,a1=0.f,a2=0.f,a3=0.f;   // producer accumulators

        // ---- P1: gates (threads 0-255) ----
        if (tid < PP){
            const float den = ((s_r2[0]+s_r2[1])+(s_r2[2]+s_r2[3]))
                            + ((s_r2[4]+s_r2[5])+(s_r2[6]+s_r2[7]));
            const float num = ((s_r2[8]+s_r2[9])+(s_r2[10]+s_r2[11]))
                            + ((s_r2[12]+s_r2[13])+(s_r2[14]+s_r2[15]));
            const float xin = num*frcp(den) + s_data[t]*s_sc2[2] + s_sc2[0];
            float z[4];
            #pragma unroll
            for (int g=0; g<4; ++g){
                const int j = tid + 256*g;
                z[g] = s_z[j] + xin*__half2float(s_Wk[j]) + s_bl[j];
            }
            const float gi = fsig(z[0]);
            const float gf = fsig(z[1]);
            const float gg = ftanh(z[2]);
            const float go = fsig(z[3]);
            const float c_new = gf*s_c[tid] + gi*gg;
            const float h_new = go*ftanh(c_new);
            s_c[tid] = c_new;
            s_h[tid] = h_new;
            s_hh[tid] = __float2half(h_new);
            s_ch[tid] = __float2half(c_new);
        }
        __syncthreads();   // bar1

        // ---- R2: consumers q-partials; producers k4 0..23 + preload 24..31 ----
        if (tid < 512){
            float4 qa = make_float4(0.f,0.f,0.f,0.f);
            const uint4* wp = W2_p + (size_t)(kc2*32)*64 + mq;
            const uint*  hbp = (kc2 < 4) ? (const uint*)s_hh : (((const uint*)s_ch) - 128);
            #pragma unroll 8
            for (int i=0;i<32;++i){
                const uint4 w = wp[(size_t)i*64];
                const uint hv = hbp[kc2*32 + i];
                qa.x = dot2f(w.x,hv,qa.x); qa.y = dot2f(w.y,hv,qa.y);
                qa.z = dot2f(w.z,hv,qa.z); qa.w = dot2f(w.w,hv,qa.w);
            }
            *(float4*)&s_red[kc2*256 + mq*4] = qa;
        } else {
            #pragma unroll
            for (int i=0;i<8;++i){
                const uint2 hp = hu2[i];
                a0=dot2f(pb[i].x,hp.x,a0); a1=dot2f(pb[i].y,hp.y,a1);
                a2=dot2f(pb[i].z,hp.x,a2); a3=dot2f(pb[i].w,hp.y,a3);
            }
            #pragma unroll
            for (int k=8;k<24;++k){
                const uint4 w = wc[(size_t)k*512];
                const uint2 hp = hu2[k];
                a0=dot2f(w.x,hp.x,a0); a1=dot2f(w.y,hp.y,a1);
                a2=dot2f(w.z,hp.x,a2); a3=dot2f(w.w,hp.y,a3);
            }
            #pragma unroll
            for (int i=0;i<8;++i) pb[i] = wc[(size_t)(24+i)*512];
        }
        __syncthreads();   // bar2

        // ---- P3: q reduce + Eq pack (threads 0-255); producers k4 24..31 + preload 32..39 ----
        if (tid < MM){
            float q = s_b2[tid];
            #pragma unroll
            for (int i=0;i<8;++i) q += s_red[i*256+tid];
            const uint eu = (uint)__half_as_ushort(__float2half(fexp2(q)));
            const uint hi = __shfl_down(eu, 1);
            if ((tid & 1) == 0) s_eqh[tid>>1] = eu | (hi<<16);
        } else if (tid >= 512){
            #pragma unroll
            for (int i=0;i<8;++i){
                const uint2 hp = hu2[24+i];
                a0=dot2f(pb[i].x,hp.x,a0); a1=dot2f(pb[i].y,hp.y,a1);
                a2=dot2f(pb[i].z,hp.x,a2); a3=dot2f(pb[i].w,hp.y,a3);
            }
            #pragma unroll
            for (int i=0;i<8;++i) pb[i] = wc[(size_t)(32+i)*512];
        }
        __syncthreads();   // bar3

        // ---- R4: consumers scores + e + sums; producers k4 32..63 + z write + preload next ----
        if (tid < 512){
            float sacc0=0.f, sacc1=0.f;
            const char* prow = (const char*)s_pre + ttx*512;
            const int rsw = (ttx&15)<<4;
            #pragma unroll
            for (int cch=0; cch<16; ++cch){
                const int cc = cch*2 + sub;
                const uint4 pv = *(const uint4*)(prow + ((cc*16) ^ rsw));
                const uint4 eq = *(const uint4*)&s_eqh[cc*4];
                const uint4 wv = *(const uint4*)&s_wvh[cc*4];
                sacc0 = term2(pv.x, eq.x, wv.x, sacc0);
                sacc1 = term2(pv.y, eq.y, wv.y, sacc1);
                sacc0 = term2(pv.z, eq.z, wv.z, sacc0);
                sacc1 = term2(pv.w, eq.w, wv.w, sacc1);
            }
            float sacc = sacc0 + sacc1;
            sacc += __shfl_xor(sacc, 1);
            float e = 0.f;
            if (sub == 0){
                e = fexp2(fmaf(-QSCALE, sacc, s_sc2[3]));   // exp2(log2e*score)
                s_score[ttx] = e;
            }
            const float pe = e * s_edot[ttx];
            const float se = wsum(e);
            const float sp = wsum(pe);
            if (lane==0){ s_r2[wid] = se; s_r2[8+wid] = sp; }
        } else {
            #pragma unroll
            for (int i=0;i<8;++i){
                const uint2 hp = hu2[32+i];
                a0=dot2f(pb[i].x,hp.x,a0); a1=dot2f(pb[i].y,hp.y,a1);
                a2=dot2f(pb[i].z,hp.x,a2); a3=dot2f(pb[i].w,hp.y,a3);
            }
            #pragma unroll
            for (int k=40;k<64;++k){
                const uint4 w = wc[(size_t)k*512];
                const uint2 hp = hu2[k];
                a0=dot2f(w.x,hp.x,a0); a1=dot2f(w.y,hp.y,a1);
                a2=dot2f(w.z,hp.x,a2); a3=dot2f(w.w,hp.y,a3);
            }
            *(float2*)&s_z[2*p] = make_float2(a0+a1, a2+a3);
            #pragma unroll
            for (int i=0;i<8;++i) pb[i] = wc[(size_t)i*512];   // next-step k4 0..7
        }
        __syncthreads();   // bar4
    }

    // ---- epilogue: ctx once from final beta (threads 0-511) ----
    if (tid < 512){
        float4 ca = make_float4(0.f,0.f,0.f,0.f);
        const float* ep = erow_b + (size_t)(kc2*32)*MM + mq*4;
        #pragma unroll 4
        for (int k=0;k<32;++k){
            const float bt = s_score[kc2*32+k];
            const float4 e = *(const float4*)(ep);
            ca.x = fmaf(bt,e.x,ca.x); ca.y = fmaf(bt,e.y,ca.y);
            ca.z = fmaf(bt,e.z,ca.z); ca.w = fmaf(bt,e.w,ca.w);
            ep += MM;
        }
        *(float4*)&s_red[kc2*256 + mq*4] = ca;
    }
    __syncthreads();
    if (tid < MM){
        const float den = ((s_r2[0]+s_r2[1])+(s_r2[2]+s_r2[3]))
                        + ((s_r2[4]+s_r2[5])+(s_r2[6]+s_r2[7]));
        const float rd = frcp(den);
        float s = 0.f;
        #pragma unroll
        for (int i=0;i<8;++i) s += s_red[i*256+tid];
        out[(size_t)b*512 + 256 + tid] = s*rd;
        out[(size_t)b*512 + tid]       = s_h[tid];
    }
}

extern "C" void kernel_launch(void* const* d_in, const int* in_sizes, int n_in,
                              void* d_out, int out_size, void* d_ws, size_t ws_size,
                              hipStream_t stream) {
    const float* data = (const float*)d_in[0];
    const float* enc  = (const float*)d_in[1];
    const float* h0   = (const float*)d_in[2];
    const float* c0   = (const float*)d_in[3];
    const float* Wd   = (const float*)d_in[4];
    const float* bd   = (const float*)d_in[5];
    const float* Wk   = (const float*)d_in[6];
    const float* Wr   = (const float*)d_in[7];
    const float* bl   = (const float*)d_in[8];
    const float* W1   = (const float*)d_in[9];
    const float* b1   = (const float*)d_in[10];
    const float* W2   = (const float*)d_in[11];
    const float* b2   = (const float*)d_in[12];
    const float* Wv   = (const float*)d_in[13];
    const float* bv   = (const float*)d_in[14];
    float* outp = (float*)d_out;

    char* ws = (char*)d_ws;
    __half* preE  = (__half*)(ws);                  // 16,777,216 B
    uint4*  Wr4   = (uint4*)(ws + 16777216);        //    524,288 B
    __half2* W2_p = (__half2*)(ws + 17301504);      //    262,144 B
    float*  edot  = (float*)(ws + 17563648);        //    131,072 B

    prep_pre<<<dim3((NB*TT)/32), dim3(256), 0, stream>>>(enc, W1, b1, preE);
    pack_wr4<<<dim3(128), dim3(256), 0, stream>>>(Wr, Wr4);
    pack_w2<<<dim3(256), dim3(256), 0, stream>>>(W2, (__half2*)W2_p);
    prep_edot<<<dim3((NB*TT)/4), dim3(256), 0, stream>>>(enc, Wd, edot);
    decoder_kernel<<<dim3(NB), dim3(1024), 0, stream>>>(
        data, enc, h0, c0, Wd, bd, Wk, bl, b2, Wv, bv,
        Wr4, (const uint4*)W2_p, preE, edot, outp);
}

// Round 8
// 2872.451 us; speedup vs baseline: 2.6806x; 2.6806x over previous
//
#include <hip/hip_runtime.h>
#include <hip/hip_fp16.h>

#define NB 128
#define TT 256
#define MM 256
#define PP 256
#define QSCALE 2.8853900817779268f   // 2*log2(e)

typedef unsigned int uint;
typedef _Float16 hf2 __attribute__((ext_vector_type(2)));

__device__ __forceinline__ float dot2f(uint a, uint b, float c){
#if defined(__AMDGCN__) && __has_builtin(__builtin_amdgcn_fdot2)
    return __builtin_amdgcn_fdot2(__builtin_bit_cast(hf2, a), __builtin_bit_cast(hf2, b), c, false);
#else
    float2 fa = __half22float2(__builtin_bit_cast(__half2, a));
    float2 fb = __half22float2(__builtin_bit_cast(__half2, b));
    return fmaf(fa.x, fb.x, fmaf(fa.y, fb.y, c));
#endif
}

__device__ __forceinline__ float frcp(float x){ return __builtin_amdgcn_rcpf(x); }
#if defined(__AMDGCN__) && __has_builtin(__builtin_amdgcn_exp2f)
__device__ __forceinline__ float fexp2(float x){ return __builtin_amdgcn_exp2f(x); }
#else
__device__ __forceinline__ float fexp2(float x){ return exp2f(x); }
#endif
__device__ __forceinline__ float fsig(float x){ return frcp(1.f + __expf(-x)); }
__device__ __forceinline__ float ftanh(float x){ return fmaf(-2.f, frcp(1.f + __expf(2.f*x)), 1.f); }

__device__ __forceinline__ float wsum(float v){
    #pragma unroll
    for(int o=32;o;o>>=1) v += __shfl_xor(v,o);
    return v;
}

// 2 tanh-terms: acc += dot2(Wv2, 1/(Ep2*Eq2+1)) with f32 accumulate
__device__ __forceinline__ float term2(uint ep, uint eq, uint wv, float acc){
    hf2 d = __builtin_bit_cast(hf2, ep) * __builtin_bit_cast(hf2, eq)
          + hf2{(_Float16)1.f, (_Float16)1.f};
    const __half2 r = h2rcp(__builtin_bit_cast(__half2, d));
    return dot2f(__builtin_bit_cast(uint, r), wv, acc);
}

// preE[row, m] = exp2(QSCALE*(enc[row]@W1[:,m] + b1[m])) -> fp16  (Ep)
__global__ __launch_bounds__(256) void prep_pre(
    const float* __restrict__ enc, const float* __restrict__ W1,
    const float* __restrict__ b1, __half* __restrict__ preE)
{
    const int row0 = blockIdx.x * 32;
    const int col  = threadIdx.x;
    float acc[32];
    const float bias = b1[col];
    #pragma unroll
    for (int r=0;r<32;++r) acc[r]=bias;
    for (int k=0;k<256;k+=4){
        const float w0 = W1[(size_t)(k+0)*256+col];
        const float w1 = W1[(size_t)(k+1)*256+col];
        const float w2 = W1[(size_t)(k+2)*256+col];
        const float w3 = W1[(size_t)(k+3)*256+col];
        #pragma unroll
        for (int r=0;r<32;++r){
            const float4 e = *(const float4*)(enc + (size_t)(row0+r)*256 + k);
            acc[r] = fmaf(e.x,w0, fmaf(e.y,w1, fmaf(e.z,w2, fmaf(e.w,w3, acc[r]))));
        }
    }
    #pragma unroll
    for (int r=0;r<32;++r) preE[(size_t)(row0+r)*256+col] = __float2half(fexp2(acc[r]*QSCALE));
}

// Wr (256,1024) f32 -> k-pair-interleaved half2: Wp[k2*1024 + j] = (Wr[2k2][j], Wr[2k2+1][j])
__global__ __launch_bounds__(256) void pack_wr(const float* __restrict__ Wr, __half2* __restrict__ Wp){
    const int idx = blockIdx.x*256 + threadIdx.x;   // 131072
    const int k2 = idx >> 10, j = idx & 1023;
    Wp[idx] = __floats2half2_rn(Wr[(size_t)(2*k2)*1024 + j], Wr[(size_t)(2*k2+1)*1024 + j]);
}
// W2 (512,256) f32 * QSCALE -> Wp[k2*256 + m]
__global__ __launch_bounds__(256) void pack_w2(const float* __restrict__ W2, __half2* __restrict__ Wp){
    const int idx = blockIdx.x*256 + threadIdx.x;   // 65536
    const int k2 = idx >> 8, m = idx & 255;
    Wp[idx] = __floats2half2_rn(W2[(size_t)(2*k2)*256 + m]*QSCALE, W2[(size_t)(2*k2+1)*256 + m]*QSCALE);
}
// edot[row] = enc[row,:] . Wd[1:257]
__global__ __launch_bounds__(256) void prep_edot(
    const float* __restrict__ enc, const float* __restrict__ Wd, float* __restrict__ edot)
{
    const int row  = blockIdx.x*4 + (threadIdx.x>>6);
    const int lane = threadIdx.x & 63;
    const float4 e = *(const float4*)(enc + (size_t)row*256 + lane*4);
    float s = e.x*Wd[1+lane*4] + e.y*Wd[2+lane*4] + e.z*Wd[3+lane*4] + e.w*Wd[4+lane*4];
    s = wsum(s);
    if (lane==0) edot[row] = s;
}

// One block per batch element; 1024 threads; 4 barriers/step.
// Waves 8-15: Wr-stream producer (z_{t+1}=h_t@Wr), uint2 direct streaming,
// split 32/16/80 k2 across R2/P3/R4. Consumers: gates, q, Ep*Eq scores with
// folded softmax (no max-subtraction; scores bounded).
__global__ __launch_bounds__(1024) void decoder_kernel(
    const float* __restrict__ data, const float* __restrict__ enc,
    const float* __restrict__ h0, const float* __restrict__ c0,
    const float* __restrict__ Wd, const float* __restrict__ bd,
    const float* __restrict__ Wk, const float* __restrict__ bl,
    const float* __restrict__ b2, const float* __restrict__ Wv,
    const float* __restrict__ bv,
    const uint2* __restrict__ Wr2,    // [128 k2][512] uint2 (2 half2 cols)
    const uint4* __restrict__ W2_p,   // [256 k2][64 uint4]
    const __half* __restrict__ preE,  // [B*T][256] Ep fp16
    const float* __restrict__ edot,   // [B*T]
    float* __restrict__ out)
{
    __shared__ __half s_pre[TT*MM];      // 131072 B (Ep, swizzled)
    __shared__ float s_red[2048];        // 8192 B
    __shared__ float s_z[1024];          // 4096 B
    __shared__ alignas(16) __half s_hh[PP];
    __shared__ alignas(16) __half s_ch[PP];
    __shared__ float s_h[PP], s_c[PP], s_score[TT];
    __shared__ float s_r2[32];
    __shared__ __half s_Wk[1024];
    __shared__ float s_bl[1024], s_b2[MM];
    __shared__ alignas(16) uint s_eqh[128];   // Eq fp16 pairs (per step)
    __shared__ alignas(16) uint s_wvh[128];   // Wv fp16 pairs
    __shared__ float s_edot[TT], s_data[TT];
    __shared__ float s_sc2[4];

    const int tid  = threadIdx.x;
    const int lane = tid & 63;
    const int wid  = tid >> 6;
    const int b    = blockIdx.x;

    s_Wk[tid] = __float2half(Wk[tid]);
    s_bl[tid] = bl[tid];
    if (tid < MM){
        s_b2[tid] = b2[tid]*QSCALE;
        const float h0v = h0[(size_t)b*PP+tid];
        const float c0v = c0[(size_t)b*PP+tid];
        s_h[tid]  = h0v;  s_hh[tid] = __float2half(h0v);
        s_c[tid]  = c0v;  s_ch[tid] = __float2half(c0v);
        s_edot[tid] = edot[(size_t)b*TT + tid];
    }
    if (tid < TT-1) s_data[tid] = data[(size_t)b*(TT-1)+tid];
    if (tid < 16) s_r2[tid] = (tid==0) ? 1.f : 0.f;   // den=1, num=0 for t=0
    if (tid < 128){
        const float2 w2 = *(const float2*)(Wv + 2*tid);
        s_wvh[tid] = __builtin_bit_cast(uint, __floats2half2_rn(w2.x, w2.y));
    }
    if (tid == 0){ s_sc2[0] = bd[0]; s_sc2[2] = Wd[0]; }
    if (tid < 64){
        const float4 w4 = *(const float4*)(Wv + 4*tid);
        float s = (w4.x+w4.y)+(w4.z+w4.w);
        s = wsum(s);
        if (tid==0) s_sc2[3] = (bv[0] + s) * (0.5f*QSCALE);   // C' = (bv+SumWv)*log2e
    }
    __syncthreads();

    const int p = tid - 512;             // producer thread id 0..511
    const uint2* wc = Wr2 + ((tid >= 512) ? p : 0);
    const uint*  hu = (const uint*)s_hh;

    // ---- prologue ----
    if (tid < 512){
        // stage Ep into LDS (swizzled): row t0 = tid>>1, 16 x 16B chunks
        const uint4* g = (const uint4*)(preE + (size_t)b*TT*MM);
        const int t0 = tid >> 1, cg = (tid & 1) * 16;
        const int rsw = (t0 & 15) << 4;
        #pragma unroll
        for (int i=0;i<16;++i){
            const int c = cg + i;
            *(uint4*)((char*)s_pre + t0*512 + ((c*16) ^ rsw)) = g[t0*32 + c];
        }
    } else {
        // z0 = h0 @ Wr (all 128 k2)
        float a0=0.f, a1=0.f;
        #pragma unroll 8
        for (int k=0;k<128;++k){
            const uint2 w = wc[(size_t)k*512];
            const uint hv = hu[k];
            a0 = dot2f(w.x,hv,a0); a1 = dot2f(w.y,hv,a1);
        }
        *(float2*)&s_z[2*p] = make_float2(a0,a1);
    }
    __syncthreads();

    const float* erow_b = enc + (size_t)b*TT*MM;
    const int mq  = tid & 63;    // R2/epilogue: m-quad
    const int kc2 = tid >> 6;    // R2: k2-chunk 0..7; epilogue: t-chunk
    const int ttx = tid >> 1;    // R4: t row
    const int sub = tid & 1;     // R4: m half

    for (int t=0; t<TT-1; ++t){
        float a0=0.f, a1=0.f;    // producer accumulators (live across barriers)

        // ---- P1: gates (threads 0-255) ----
        if (tid < PP){
            const float den = ((s_r2[0]+s_r2[1])+(s_r2[2]+s_r2[3]))
                            + ((s_r2[4]+s_r2[5])+(s_r2[6]+s_r2[7]));
            const float num = ((s_r2[8]+s_r2[9])+(s_r2[10]+s_r2[11]))
                            + ((s_r2[12]+s_r2[13])+(s_r2[14]+s_r2[15]));
            const float xin = num*frcp(den) + s_data[t]*s_sc2[2] + s_sc2[0];
            float z[4];
            #pragma unroll
            for (int g=0; g<4; ++g){
                const int j = tid + 256*g;
                z[g] = s_z[j] + xin*__half2float(s_Wk[j]) + s_bl[j];
            }
            const float gi = fsig(z[0]);
            const float gf = fsig(z[1]);
            const float gg = ftanh(z[2]);
            const float go = fsig(z[3]);
            const float c_new = gf*s_c[tid] + gi*gg;
            const float h_new = go*ftanh(c_new);
            s_c[tid] = c_new;
            s_h[tid] = h_new;
            s_hh[tid] = __float2half(h_new);
            s_ch[tid] = __float2half(c_new);
        }
        __syncthreads();   // bar1

        // ---- R2: consumers q-partials; producers Wr k2 0..31 ----
        if (tid < 512){
            float4 qa = make_float4(0.f,0.f,0.f,0.f);
            const uint4* wp = W2_p + (size_t)(kc2*32)*64 + mq;
            const uint*  hbp = (kc2 < 4) ? (const uint*)s_hh : (((const uint*)s_ch) - 128);
            #pragma unroll 8
            for (int i=0;i<32;++i){
                const uint4 w = wp[(size_t)i*64];
                const uint hv = hbp[kc2*32 + i];
                qa.x = dot2f(w.x,hv,qa.x); qa.y = dot2f(w.y,hv,qa.y);
                qa.z = dot2f(w.z,hv,qa.z); qa.w = dot2f(w.w,hv,qa.w);
            }
            *(float4*)&s_red[kc2*256 + mq*4] = qa;
        } else {
            #pragma unroll 8
            for (int k=0;k<32;++k){
                const uint2 w = wc[(size_t)k*512];
                const uint hv = hu[k];
                a0 = dot2f(w.x,hv,a0); a1 = dot2f(w.y,hv,a1);
            }
        }
        __syncthreads();   // bar2

        // ---- P3: consumers (0-255) q reduce + Eq pack; producers Wr k2 32..47 ----
        if (tid < MM){
            float q = s_b2[tid];
            #pragma unroll
            for (int i=0;i<8;++i) q += s_red[i*256+tid];
            const uint eu = (uint)__half_as_ushort(__float2half(fexp2(q)));
            const uint hi = __shfl_down(eu, 1);
            if ((tid & 1) == 0) s_eqh[tid>>1] = eu | (hi<<16);
        } else if (tid >= 512){
            #pragma unroll 8
            for (int k=32;k<48;++k){
                const uint2 w = wc[(size_t)k*512];
                const uint hv = hu[k];
                a0 = dot2f(w.x,hv,a0); a1 = dot2f(w.y,hv,a1);
            }
        }
        __syncthreads();   // bar3

        // ---- R4: consumers scores (Ep*Eq) + e + sums; producers Wr k2 48..127 + z write ----
        if (tid < 512){
            float sacc0=0.f, sacc1=0.f;
            const char* prow = (const char*)s_pre + ttx*512;
            const int rsw = (ttx&15)<<4;
            #pragma unroll
            for (int cch=0; cch<16; ++cch){
                const int cc = cch*2 + sub;
                const uint4 pv = *(const uint4*)(prow + ((cc*16) ^ rsw));
                const uint4 eq = *(const uint4*)&s_eqh[cc*4];
                const uint4 wv = *(const uint4*)&s_wvh[cc*4];
                sacc0 = term2(pv.x, eq.x, wv.x, sacc0);
                sacc1 = term2(pv.y, eq.y, wv.y, sacc1);
                sacc0 = term2(pv.z, eq.z, wv.z, sacc0);
                sacc1 = term2(pv.w, eq.w, wv.w, sacc1);
            }
            float sacc = sacc0 + sacc1;
            sacc += __shfl_xor(sacc, 1);
            float e = 0.f;
            if (sub == 0){
                e = fexp2(fmaf(-QSCALE, sacc, s_sc2[3]));   // exp2(log2e*score)
                s_score[ttx] = e;
            }
            const float pe = e * s_edot[ttx];
            const float se = wsum(e);
            const float sp = wsum(pe);
            if (lane==0){ s_r2[wid] = se; s_r2[8+wid] = sp; }
        } else {
            #pragma unroll 8
            for (int k=48;k<128;++k){
                const uint2 w = wc[(size_t)k*512];
                const uint hv = hu[k];
                a0 = dot2f(w.x,hv,a0); a1 = dot2f(w.y,hv,a1);
            }
            *(float2*)&s_z[2*p] = make_float2(a0,a1);
        }
        __syncthreads();   // bar4
    }

    // ---- epilogue: ctx once from final beta (threads 0-511) ----
    if (tid < 512){
        float4 ca = make_float4(0.f,0.f,0.f,0.f);
        const float* ep = erow_b + (size_t)(kc2*32)*MM + mq*4;
        #pragma unroll 4
        for (int k=0;k<32;++k){
            const float bt = s_score[kc2*32+k];
            const float4 e = *(const float4*)(ep);
            ca.x = fmaf(bt,e.x,ca.x); ca.y = fmaf(bt,e.y,ca.y);
            ca.z = fmaf(bt,e.z,ca.z); ca.w = fmaf(bt,e.w,ca.w);
            ep += MM;
        }
        *(float4*)&s_red[kc2*256 + mq*4] = ca;
    }
    __syncthreads();
    if (tid < MM){
        const float den = ((s_r2[0]+s_r2[1])+(s_r2[2]+s_r2[3]))
                        + ((s_r2[4]+s_r2[5])+(s_r2[6]+s_r2[7]));
        const float rd = frcp(den);
        float s = 0.f;
        #pragma unroll
        for (int i=0;i<8;++i) s += s_red[i*256+tid];
        out[(size_t)b*512 + 256 + tid] = s*rd;
        out[(size_t)b*512 + tid]       = s_h[tid];
    }
}

extern "C" void kernel_launch(void* const* d_in, const int* in_sizes, int n_in,
                              void* d_out, int out_size, void* d_ws, size_t ws_size,
                              hipStream_t stream) {
    const float* data = (const float*)d_in[0];
    const float* enc  = (const float*)d_in[1];
    const float* h0   = (const float*)d_in[2];
    const float* c0   = (const float*)d_in[3];
    const float* Wd   = (const float*)d_in[4];
    const float* bd   = (const float*)d_in[5];
    const float* Wk   = (const float*)d_in[6];
    const float* Wr   = (const float*)d_in[7];
    const float* bl   = (const float*)d_in[8];
    const float* W1   = (const float*)d_in[9];
    const float* b1   = (const float*)d_in[10];
    const float* W2   = (const float*)d_in[11];
    const float* b2   = (const float*)d_in[12];
    const float* Wv   = (const float*)d_in[13];
    const float* bv   = (const float*)d_in[14];
    float* outp = (float*)d_out;

    char* ws = (char*)d_ws;
    __half*  preE = (__half*)(ws);                  // 16,777,216 B
    __half2* Wr_p = (__half2*)(ws + 16777216);      //    524,288 B
    __half2* W2_p = (__half2*)(ws + 17301504);      //    262,144 B
    float*   edot = (float*)(ws + 17563648);        //    131,072 B

    prep_pre<<<dim3((NB*TT)/32), dim3(256), 0, stream>>>(enc, W1, b1, preE);
    pack_wr<<<dim3(512), dim3(256), 0, stream>>>(Wr, Wr_p);
    pack_w2<<<dim3(256), dim3(256), 0, stream>>>(W2, (__half2*)W2_p);
    prep_edot<<<dim3((NB*TT)/4), dim3(256), 0, stream>>>(enc, Wd, edot);
    decoder_kernel<<<dim3(NB), dim3(1024), 0, stream>>>(
        data, enc, h0, c0, Wd, bd, Wk, bl, b2, Wv, bv,
        (const uint2*)Wr_p, (const uint4*)W2_p, preE, edot, outp);
}

// Round 9
// 2582.246 us; speedup vs baseline: 2.9818x; 1.1124x over previous
//
#include <hip/hip_runtime.h>
#include <hip/hip_fp16.h>

#define NB 128
#define TT 256
#define MM 256
#define PP 256
#define QSCALE 2.8853900817779268f   // 2*log2(e)

typedef unsigned int uint;
typedef _Float16 hf2 __attribute__((ext_vector_type(2)));

__device__ __forceinline__ float dot2f(uint a, uint b, float c){
#if defined(__AMDGCN__) && __has_builtin(__builtin_amdgcn_fdot2)
    return __builtin_amdgcn_fdot2(__builtin_bit_cast(hf2, a), __builtin_bit_cast(hf2, b), c, false);
#else
    float2 fa = __half22float2(__builtin_bit_cast(__half2, a));
    float2 fb = __half22float2(__builtin_bit_cast(__half2, b));
    return fmaf(fa.x, fb.x, fmaf(fa.y, fb.y, c));
#endif
}

__device__ __forceinline__ float frcp(float x){ return __builtin_amdgcn_rcpf(x); }
#if defined(__AMDGCN__) && __has_builtin(__builtin_amdgcn_exp2f)
__device__ __forceinline__ float fexp2(float x){ return __builtin_amdgcn_exp2f(x); }
#else
__device__ __forceinline__ float fexp2(float x){ return exp2f(x); }
#endif
__device__ __forceinline__ float fsig(float x){ return frcp(1.f + __expf(-x)); }
__device__ __forceinline__ float ftanh(float x){ return fmaf(-2.f, frcp(1.f + __expf(2.f*x)), 1.f); }

// 2 tanh-terms: acc += dot2(Wv2, 1/(Ep2*Eq2+1)) with f32 accumulate
__device__ __forceinline__ float term2(uint ep, uint eq, uint wv, float acc){
    hf2 d = __builtin_bit_cast(hf2, ep) * __builtin_bit_cast(hf2, eq)
          + hf2{(_Float16)1.f, (_Float16)1.f};
    const __half2 r = h2rcp(__builtin_bit_cast(__half2, d));
    return dot2f(__builtin_bit_cast(uint, r), wv, acc);
}

__device__ __forceinline__ float wsum(float v){
    #pragma unroll
    for(int o=32;o;o>>=1) v += __shfl_xor(v,o);
    return v;
}

// preE[row, m] = exp2(QSCALE*(enc[row]@W1[:,m] + b1[m])) -> fp16  (Ep)
__global__ __launch_bounds__(256) void prep_pre(
    const float* __restrict__ enc, const float* __restrict__ W1,
    const float* __restrict__ b1, __half* __restrict__ preE)
{
    const int row0 = blockIdx.x * 32;
    const int col  = threadIdx.x;
    float acc[32];
    const float bias = b1[col];
    #pragma unroll
    for (int r=0;r<32;++r) acc[r]=bias;
    for (int k=0;k<256;k+=4){
        const float w0 = W1[(size_t)(k+0)*256+col];
        const float w1 = W1[(size_t)(k+1)*256+col];
        const float w2 = W1[(size_t)(k+2)*256+col];
        const float w3 = W1[(size_t)(k+3)*256+col];
        #pragma unroll
        for (int r=0;r<32;++r){
            const float4 e = *(const float4*)(enc + (size_t)(row0+r)*256 + k);
            acc[r] = fmaf(e.x,w0, fmaf(e.y,w1, fmaf(e.z,w2, fmaf(e.w,w3, acc[r]))));
        }
    }
    #pragma unroll
    for (int r=0;r<32;++r) preE[(size_t)(row0+r)*256+col] = __float2half(fexp2(acc[r]*QSCALE));
}

// Wr (256,1024) f32 -> Wr4[k4][j2] uint4: (k..k+1,k+2..k+3) x cols (j, j+1)
__global__ __launch_bounds__(256) void pack_wr4(const float* __restrict__ Wr, uint4* __restrict__ Wp){
    const int idx = blockIdx.x*256 + threadIdx.x;   // 32768
    const int k4 = idx >> 9, j2 = idx & 511;
    const int k = 4*k4, j = 2*j2;
    const __half2 x = __floats2half2_rn(Wr[(size_t)(k+0)*1024+j],   Wr[(size_t)(k+1)*1024+j]);
    const __half2 y = __floats2half2_rn(Wr[(size_t)(k+2)*1024+j],   Wr[(size_t)(k+3)*1024+j]);
    const __half2 z = __floats2half2_rn(Wr[(size_t)(k+0)*1024+j+1], Wr[(size_t)(k+1)*1024+j+1]);
    const __half2 w = __floats2half2_rn(Wr[(size_t)(k+2)*1024+j+1], Wr[(size_t)(k+3)*1024+j+1]);
    Wp[idx] = make_uint4(__builtin_bit_cast(uint,x), __builtin_bit_cast(uint,y),
                         __builtin_bit_cast(uint,z), __builtin_bit_cast(uint,w));
}
// W2 (512,256) f32 * QSCALE -> W2q[k8][sub][m] uint4 = 4 local k2 (8 k) of half `sub`, col m
__global__ __launch_bounds__(256) void pack_w2q(const float* __restrict__ W2, uint4* __restrict__ Wq){
    const int idx = blockIdx.x*256 + threadIdx.x;   // 16384
    const int k8 = idx >> 9, sub = (idx >> 8) & 1, m = idx & 255;
    uint o[4];
    #pragma unroll
    for (int j=0;j<4;++j){
        const int gk2 = sub*128 + k8*4 + j;
        o[j] = __builtin_bit_cast(uint, __floats2half2_rn(
            W2[(size_t)(2*gk2)*256 + m]*QSCALE, W2[(size_t)(2*gk2+1)*256 + m]*QSCALE));
    }
    Wq[idx] = make_uint4(o[0],o[1],o[2],o[3]);
}
// edot[row] = enc[row,:] . Wd[1:257]
__global__ __launch_bounds__(256) void prep_edot(
    const float* __restrict__ enc, const float* __restrict__ Wd, float* __restrict__ edot)
{
    const int row  = blockIdx.x*4 + (threadIdx.x>>6);
    const int lane = threadIdx.x & 63;
    const float4 e = *(const float4*)(enc + (size_t)row*256 + lane*4);
    float s = e.x*Wd[1+lane*4] + e.y*Wd[2+lane*4] + e.z*Wd[3+lane*4] + e.w*Wd[4+lane*4];
    s = wsum(s);
    if (lane==0) edot[row] = s;
}

// One block per batch element; 1024 threads; 3 barriers/step.
// Waves 8-15: Wr producer (uint4 stream, 4 accumulators, split 20/44 k4 over R2/R4).
// Consumers: P1 gates (256t); R2 shfl-paired q matvec (512t, no reduce phase);
// R4 Ep*Eq scores + folded softmax sums.
__global__ __launch_bounds__(1024) void decoder_kernel(
    const float* __restrict__ data, const float* __restrict__ enc,
    const float* __restrict__ h0, const float* __restrict__ c0,
    const float* __restrict__ Wd, const float* __restrict__ bd,
    const float* __restrict__ Wk, const float* __restrict__ bl,
    const float* __restrict__ b2, const float* __restrict__ Wv,
    const float* __restrict__ bv,
    const uint4* __restrict__ Wr4,    // [64 k4][512 j2]
    const uint4* __restrict__ W2q,    // [32 k8][2 sub][256 m]
    const __half* __restrict__ preE,  // [B*T][256] Ep fp16
    const float* __restrict__ edot,   // [B*T]
    float* __restrict__ out)
{
    __shared__ __half s_pre[TT*MM];      // 131072 B (Ep, swizzled)
    __shared__ float s_red[2048];        // 8192 B (epilogue only)
    __shared__ float s_z[1024];          // 4096 B
    __shared__ alignas(16) __half s_hh[PP];
    __shared__ alignas(16) __half s_ch[PP];
    __shared__ float s_h[PP], s_c[PP], s_score[TT];
    __shared__ float s_r2[32];
    __shared__ __half s_Wk[1024];
    __shared__ float s_bl[1024], s_b2[MM];
    __shared__ alignas(16) uint s_eqh[128];   // Eq fp16 pairs (per step)
    __shared__ alignas(16) uint s_wvh[128];   // Wv fp16 pairs
    __shared__ float s_edot[TT], s_data[TT];
    __shared__ float s_sc2[4];

    const int tid  = threadIdx.x;
    const int lane = tid & 63;
    const int wid  = tid >> 6;
    const int b    = blockIdx.x;

    s_Wk[tid] = __float2half(Wk[tid]);
    s_bl[tid] = bl[tid];
    if (tid < MM){
        s_b2[tid] = b2[tid]*QSCALE;
        const float h0v = h0[(size_t)b*PP+tid];
        const float c0v = c0[(size_t)b*PP+tid];
        s_h[tid]  = h0v;  s_hh[tid] = __float2half(h0v);
        s_c[tid]  = c0v;  s_ch[tid] = __float2half(c0v);
        s_edot[tid] = edot[(size_t)b*TT + tid];
    }
    if (tid < TT-1) s_data[tid] = data[(size_t)b*(TT-1)+tid];
    if (tid < 16) s_r2[tid] = (tid==0) ? 1.f : 0.f;   // den=1, num=0 for t=0
    if (tid < 128){
        const float2 w2 = *(const float2*)(Wv + 2*tid);
        s_wvh[tid] = __builtin_bit_cast(uint, __floats2half2_rn(w2.x, w2.y));
    }
    if (tid == 0){ s_sc2[0] = bd[0]; s_sc2[2] = Wd[0]; }
    if (tid < 64){
        const float4 w4 = *(const float4*)(Wv + 4*tid);
        float s = (w4.x+w4.y)+(w4.z+w4.w);
        s = wsum(s);
        if (tid==0) s_sc2[3] = (bv[0] + s) * (0.5f*QSCALE);   // C' = (bv+SumWv)*log2e
    }
    __syncthreads();

    const int p = tid - 512;             // producer thread id 0..511
    const uint4* wc = Wr4 + ((tid >= 512) ? p : 0);
    const uint2* hu2 = (const uint2*)s_hh;

    // ---- prologue ----
    if (tid < 512){
        // stage Ep into LDS (swizzled): row t0 = tid>>1, 16 x 16B chunks
        const uint4* g = (const uint4*)(preE + (size_t)b*TT*MM);
        const int t0 = tid >> 1, cg = (tid & 1) * 16;
        const int rsw = (t0 & 15) << 4;
        #pragma unroll
        for (int i=0;i<16;++i){
            const int c = cg + i;
            *(uint4*)((char*)s_pre + t0*512 + ((c*16) ^ rsw)) = g[t0*32 + c];
        }
    } else {
        // z0 = h0 @ Wr (all 64 k4)
        float a0=0.f,a1=0.f,a2=0.f,a3=0.f;
        #pragma unroll 8
        for (int k=0;k<64;++k){
            const uint4 w = wc[(size_t)k*512];
            const uint2 hp = hu2[k];
            a0=dot2f(w.x,hp.x,a0); a1=dot2f(w.y,hp.y,a1);
            a2=dot2f(w.z,hp.x,a2); a3=dot2f(w.w,hp.y,a3);
        }
        *(float2*)&s_z[2*p] = make_float2(a0+a1, a2+a3);
    }
    __syncthreads();

    const float* erow_b = enc + (size_t)b*TT*MM;
    const int mq  = tid & 63;    // epilogue: m-quad
    const int kc2 = tid >> 6;    // epilogue: t-chunk
    const int qm  = tid >> 1;    // R2: m index (0..255)
    const int qs  = tid & 1;     // R2: k-half (0=h, 1=c)
    const int ttx = tid >> 1;    // R4: t row
    const int sub = tid & 1;     // R4: m half

    for (int t=0; t<TT-1; ++t){
        float a0=0.f,a1=0.f,a2=0.f,a3=0.f;   // producer accumulators

        // ---- P1: gates (threads 0-255) ----
        if (tid < PP){
            const float den = ((s_r2[0]+s_r2[1])+(s_r2[2]+s_r2[3]))
                            + ((s_r2[4]+s_r2[5])+(s_r2[6]+s_r2[7]));
            const float num = ((s_r2[8]+s_r2[9])+(s_r2[10]+s_r2[11]))
                            + ((s_r2[12]+s_r2[13])+(s_r2[14]+s_r2[15]));
            const float xin = num*frcp(den) + s_data[t]*s_sc2[2] + s_sc2[0];
            float z[4];
            #pragma unroll
            for (int g=0; g<4; ++g){
                const int j = tid + 256*g;
                z[g] = s_z[j] + xin*__half2float(s_Wk[j]) + s_bl[j];
            }
            const float gi = fsig(z[0]);
            const float gf = fsig(z[1]);
            const float gg = ftanh(z[2]);
            const float go = fsig(z[3]);
            const float c_new = gf*s_c[tid] + gi*gg;
            const float h_new = go*ftanh(c_new);
            s_c[tid] = c_new;
            s_h[tid] = h_new;
            s_hh[tid] = __float2half(h_new);
            s_ch[tid] = __float2half(c_new);
        }
        __syncthreads();   // bar1

        // ---- R2: consumers shfl-paired q + Eq pack; producers Wr k4 0..19 ----
        if (tid < 512){
            float q0=0.f,q1=0.f,q2=0.f,q3=0.f;
            const uint4* wp = W2q + qs*256 + qm;
            const uint4* hb4 = qs ? (const uint4*)s_ch : (const uint4*)s_hh;
            #pragma unroll 8
            for (int k8=0;k8<32;++k8){
                const uint4 w  = wp[(size_t)k8*512];
                const uint4 h4 = hb4[k8];
                q0=dot2f(w.x,h4.x,q0); q1=dot2f(w.y,h4.y,q1);
                q2=dot2f(w.z,h4.z,q2); q3=dot2f(w.w,h4.w,q3);
            }
            float qh = (q0+q1)+(q2+q3);
            const float qfull = qh + __shfl_xor(qh,1) + s_b2[qm];
            const uint eu = (uint)__half_as_ushort(__float2half(fexp2(qfull)));
            const uint hi = __shfl_down(eu, 2);
            if ((tid & 3) == 0) s_eqh[tid>>2] = eu | (hi<<16);
        } else {
            #pragma unroll 5
            for (int k=0;k<20;++k){
                const uint4 w = wc[(size_t)k*512];
                const uint2 hp = hu2[k];
                a0=dot2f(w.x,hp.x,a0); a1=dot2f(w.y,hp.y,a1);
                a2=dot2f(w.z,hp.x,a2); a3=dot2f(w.w,hp.y,a3);
            }
        }
        __syncthreads();   // bar2

        // ---- R4: consumers scores (Ep*Eq) + e + sums; producers Wr k4 20..63 + z write ----
        if (tid < 512){
            float sacc0=0.f, sacc1=0.f;
            const char* prow = (const char*)s_pre + ttx*512;
            const int rsw = (ttx&15)<<4;
            #pragma unroll
            for (int cch=0; cch<16; ++cch){
                const int cc = cch*2 + sub;
                const uint4 pv = *(const uint4*)(prow + ((cc*16) ^ rsw));
                const uint4 eq = *(const uint4*)&s_eqh[cc*4];
                const uint4 wv = *(const uint4*)&s_wvh[cc*4];
                sacc0 = term2(pv.x, eq.x, wv.x, sacc0);
                sacc1 = term2(pv.y, eq.y, wv.y, sacc1);
                sacc0 = term2(pv.z, eq.z, wv.z, sacc0);
                sacc1 = term2(pv.w, eq.w, wv.w, sacc1);
            }
            float sacc = sacc0 + sacc1;
            sacc += __shfl_xor(sacc, 1);
            float e = 0.f;
            if (sub == 0){
                e = fexp2(fmaf(-QSCALE, sacc, s_sc2[3]));   // exp2(log2e*score)
                s_score[ttx] = e;
            }
            float se = e, sp = e * s_edot[ttx];
            #pragma unroll
            for (int o=32;o;o>>=1){
                const float t1 = __shfl_xor(se,o);
                const float t2 = __shfl_xor(sp,o);
                se += t1; sp += t2;
            }
            if (lane==0){ s_r2[wid] = se; s_r2[8+wid] = sp; }
        } else {
            #pragma unroll 8
            for (int k=20;k<64;++k){
                const uint4 w = wc[(size_t)k*512];
                const uint2 hp = hu2[k];
                a0=dot2f(w.x,hp.x,a0); a1=dot2f(w.y,hp.y,a1);
                a2=dot2f(w.z,hp.x,a2); a3=dot2f(w.w,hp.y,a3);
            }
            *(float2*)&s_z[2*p] = make_float2(a0+a1, a2+a3);
        }
        __syncthreads();   // bar3
    }

    // ---- epilogue: ctx once from final beta (threads 0-511) ----
    if (tid < 512){
        float4 ca = make_float4(0.f,0.f,0.f,0.f);
        const float* ep = erow_b + (size_t)(kc2*32)*MM + mq*4;
        #pragma unroll 4
        for (int k=0;k<32;++k){
            const float bt = s_score[kc2*32+k];
            const float4 e = *(const float4*)(ep);
            ca.x = fmaf(bt,e.x,ca.x); ca.y = fmaf(bt,e.y,ca.y);
            ca.z = fmaf(bt,e.z,ca.z); ca.w = fmaf(bt,e.w,ca.w);
            ep += MM;
        }
        *(float4*)&s_red[kc2*256 + mq*4] = ca;
    }
    __syncthreads();
    if (tid < MM){
        const float den = ((s_r2[0]+s_r2[1])+(s_r2[2]+s_r2[3]))
                        + ((s_r2[4]+s_r2[5])+(s_r2[6]+s_r2[7]));
        const float rd = frcp(den);
        float s = 0.f;
        #pragma unroll
        for (int i=0;i<8;++i) s += s_red[i*256+tid];
        out[(size_t)b*512 + 256 + tid] = s*rd;
        out[(size_t)b*512 + tid]       = s_h[tid];
    }
}

extern "C" void kernel_launch(void* const* d_in, const int* in_sizes, int n_in,
                              void* d_out, int out_size, void* d_ws, size_t ws_size,
                              hipStream_t stream) {
    const float* data = (const float*)d_in[0];
    const float* enc  = (const float*)d_in[1];
    const float* h0   = (const float*)d_in[2];
    const float* c0   = (const float*)d_in[3];
    const float* Wd   = (const float*)d_in[4];
    const float* bd   = (const float*)d_in[5];
    const float* Wk   = (const float*)d_in[6];
    const float* Wr   = (const float*)d_in[7];
    const float* bl   = (const float*)d_in[8];
    const float* W1   = (const float*)d_in[9];
    const float* b1   = (const float*)d_in[10];
    const float* W2   = (const float*)d_in[11];
    const float* b2   = (const float*)d_in[12];
    const float* Wv   = (const float*)d_in[13];
    const float* bv   = (const float*)d_in[14];
    float* outp = (float*)d_out;

    char* ws = (char*)d_ws;
    __half* preE = (__half*)(ws);                  // 16,777,216 B
    uint4*  Wr4  = (uint4*)(ws + 16777216);        //    524,288 B
    uint4*  W2q  = (uint4*)(ws + 17301504);        //    262,144 B
    float*  edot = (float*)(ws + 17563648);        //    131,072 B

    prep_pre<<<dim3((NB*TT)/32), dim3(256), 0, stream>>>(enc, W1, b1, preE);
    pack_wr4<<<dim3(128), dim3(256), 0, stream>>>(Wr, Wr4);
    pack_w2q<<<dim3(64), dim3(256), 0, stream>>>(W2, W2q);
    prep_edot<<<dim3((NB*TT)/4), dim3(256), 0, stream>>>(enc, Wd, edot);
    decoder_kernel<<<dim3(NB), dim3(1024), 0, stream>>>(
        data, enc, h0, c0, Wd, bd, Wk, bl, b2, Wv, bv,
        Wr4, W2q, preE, edot, outp);
}